// Round 6
// baseline (10634.254 us; speedup 1.0000x reference)
//
#include <hip/hip_runtime.h>
#include <hip/hip_bf16.h>
#include <math.h>

#define BB 16
#define SS 512
#define HH 16
#define DD 64
#define HID 1024
#define DI 768
#define DT 512

typedef unsigned short u16;

__device__ __forceinline__ float b2f(u16 u) {
    return __uint_as_float(((unsigned int)u) << 16);
}
__device__ __forceinline__ u16 f2b(float f) {
    __hip_bfloat16 h = __float2bfloat16(f);
    return *reinterpret_cast<u16*>(&h);
}
__device__ __forceinline__ void unpack8(const uint4 p, float* f) {
    unsigned int u[4] = {p.x, p.y, p.z, p.w};
#pragma unroll
    for (int i = 0; i < 4; ++i) {
        f[2*i]   = __uint_as_float(u[i] << 16);
        f[2*i+1] = __uint_as_float(u[i] & 0xffff0000u);
    }
}

// ---------------------------------------------------------------------------
// K1: y = x @ W^T + b ; LayerNorm(y)*g+bln ; l2-normalize ; *0.125
// VERIFIED in round 5 — unchanged.
// ---------------------------------------------------------------------------
template<int K>
__global__ __launch_bounds__(256)
void proj_ln_kernel(const float* __restrict__ x,
                    const float* __restrict__ w,
                    const float* __restrict__ bias,
                    const float* __restrict__ g,
                    const float* __restrict__ bln,
                    u16* __restrict__ outp)
{
    __shared__ float x_lds[4][K];
    __shared__ float y_lds[4][HID];
    const int t = threadIdx.x;
    const int row0 = blockIdx.x * 4;

    for (int idx = t; idx < K; idx += 256) {
        int r = idx / (K/4), c4 = idx % (K/4);
        reinterpret_cast<float4*>(&x_lds[r][0])[c4] =
            reinterpret_cast<const float4*>(x + (size_t)(row0 + r)*K)[c4];
    }
    __syncthreads();

    float acc[4][4];
#pragma unroll
    for (int a = 0; a < 4; ++a)
#pragma unroll
        for (int r = 0; r < 4; ++r) acc[a][r] = 0.f;

    for (int k0 = 0; k0 < K; k0 += 8) {
        float xv[4][8];
#pragma unroll
        for (int r = 0; r < 4; ++r) {
            float4 a0 = *reinterpret_cast<const float4*>(&x_lds[r][k0]);
            float4 a1 = *reinterpret_cast<const float4*>(&x_lds[r][k0+4]);
            xv[r][0]=a0.x; xv[r][1]=a0.y; xv[r][2]=a0.z; xv[r][3]=a0.w;
            xv[r][4]=a1.x; xv[r][5]=a1.y; xv[r][6]=a1.z; xv[r][7]=a1.w;
        }
#pragma unroll
        for (int jj = 0; jj < 4; ++jj) {
            const int j = t + 256*jj;
            const float* wrow = w + (size_t)j*K + k0;
            float4 w0 = *reinterpret_cast<const float4*>(wrow);
            float4 w1 = *reinterpret_cast<const float4*>(wrow + 4);
            float wf[8] = {w0.x,w0.y,w0.z,w0.w,w1.x,w1.y,w1.z,w1.w};
#pragma unroll
            for (int e = 0; e < 8; ++e)
#pragma unroll
                for (int r = 0; r < 4; ++r)
                    acc[jj][r] += xv[r][e] * wf[e];
        }
    }

#pragma unroll
    for (int jj = 0; jj < 4; ++jj) {
        float bj = bias[t + 256*jj];
#pragma unroll
        for (int r = 0; r < 4; ++r)
            y_lds[r][t + 256*jj] = acc[jj][r] + bj;
    }
    __syncthreads();

    const int lane = t & 63, wid = t >> 6;
    float s1 = 0.f, s2 = 0.f;
#pragma unroll
    for (int i = 0; i < 16; ++i) {
        float v = y_lds[wid][lane + 64*i];
        s1 += v; s2 += v*v;
    }
#pragma unroll
    for (int off = 32; off > 0; off >>= 1) {
        s1 += __shfl_down(s1, off);
        s2 += __shfl_down(s2, off);
    }
    s1 = __shfl(s1, 0); s2 = __shfl(s2, 0);
    const float mu = s1 * (1.f/1024.f);
    const float var = s2 * (1.f/1024.f) - mu*mu;
    const float rstd = rsqrtf(var + 1e-5f);

    float lv[16]; float sq = 0.f;
#pragma unroll
    for (int i = 0; i < 16; ++i) {
        int j = lane + 64*i;
        float z = (y_lds[wid][j] - mu) * rstd;
        lv[i] = z * g[j] + bln[j];
        sq += lv[i]*lv[i];
    }
#pragma unroll
    for (int off = 32; off > 0; off >>= 1) sq += __shfl_down(sq, off);
    sq = __shfl(sq, 0);
    const float sc = 0.125f / fmaxf(sqrtf(sq), 1e-12f);

    const int row = row0 + wid;
    const int b = row >> 9;
    const int s = row & 511;
#pragma unroll
    for (int i = 0; i < 16; ++i)
        outp[(((size_t)(b*HH + i)*SS + s) << 6) + lane] = f2b(lv[i] * sc);
}

// ---------------------------------------------------------------------------
// K2: ONE cross-attention phase per block. Grid = B*H*4qtiles*2phases = 2048.
// 128 threads; thread = one query row. K/V on the fly; weights bf16 in LDS
// (44 KB total). Writes the attention delta (before residual) to ws as bf16.
// ---------------------------------------------------------------------------
__global__ __launch_bounds__(128)
void attn_kernel(const u16* __restrict__ ci,
                 const u16* __restrict__ ct,
                 const float* __restrict__ w_i2t_in,  const float* __restrict__ b_i2t_in,
                 const float* __restrict__ w_i2t_out, const float* __restrict__ b_i2t_out,
                 const float* __restrict__ w_t2i_in,  const float* __restrict__ b_t2i_in,
                 const float* __restrict__ w_t2i_out, const float* __restrict__ b_t2i_out,
                 u16* __restrict__ ai,   // i2t delta (B,H,S,D) bf16
                 u16* __restrict__ at)   // t2i delta
{
    __shared__ u16   wq_lds[64][64];      // bf16 weights, 8 KB each
    __shared__ u16   wk_lds[64][64];
    __shared__ u16   wv_lds[64][64];      // later reused for Wo
    __shared__ u16   xkv[32][64];         // kv-input tile, bf16 (4 KB)
    __shared__ float k_lds[32][64];       // 8 KB
    __shared__ float v_lds[32][64];       // 8 KB   → total 44 KB

    const int t = threadIdx.x;
    const int blk = blockIdx.x;           // ph | qt | bh
    const int ph = blk & 1;
    const int qt = (blk >> 1) & 3;
    const int bh = blk >> 3;
    const int h = bh & 15;
    const int q_idx = qt*128 + t;
    const size_t qrow = ((size_t)bh*SS + q_idx) * DD;

    const u16* qsrc = ph ? ct : ci;
    const u16* ksrc = ph ? ci : ct;       // kv input
    const float* inw  = ph ? w_t2i_in  : w_i2t_in;
    const float* inb  = ph ? b_t2i_in  : b_i2t_in;
    const float* outw = ph ? w_t2i_out : w_i2t_out;
    const float* outb = ph ? b_t2i_out : b_i2t_out;
    u16* dst = ph ? at : ai;

    // ---- stage Wq, Wk, Wv as bf16 ----
    for (int idx = t; idx < 4096; idx += 128) {
        const int r = idx >> 6, c = idx & 63;
        wq_lds[r][c] = f2b(inw[(size_t)h*12288 + idx]);
        wk_lds[r][c] = f2b(inw[(size_t)h*12288 + 4096 + idx]);
        wv_lds[r][c] = f2b(inw[(size_t)h*12288 + 8192 + idx]);
    }
    const int ecol = t & 63;
    const int jh   = t >> 6;              // 0..1
    const float bk = inb[h*192 + 64  + ecol];
    const float bv = inb[h*192 + 128 + ecol];
    __syncthreads();

    // ---- q = (x @ Wq^T + bq) * 0.125 ----
    float xin[64];
#pragma unroll
    for (int c = 0; c < 8; ++c) {
        uint4 a = *reinterpret_cast<const uint4*>(qsrc + qrow + 8*c);
        unpack8(a, &xin[8*c]);
    }
    float q[64];
#pragma unroll
    for (int e = 0; e < 64; ++e) {
        float a = 0.f;
#pragma unroll
        for (int c = 0; c < 8; ++c) {
            uint4 wp = *reinterpret_cast<const uint4*>(&wq_lds[e][8*c]);
            float wf[8]; unpack8(wp, wf);
#pragma unroll
            for (int d = 0; d < 8; ++d) a += xin[8*c + d] * wf[d];
        }
        q[e] = (a + inb[h*192 + e]) * 0.125f;
    }

    // ---- flash loop over key tiles ----
    float m = -3.0e38f, l = 0.f;
    float o[64];
#pragma unroll
    for (int e = 0; e < 64; ++e) o[e] = 0.f;

    for (int kt0 = 0; kt0 < SS; kt0 += 32) {
        __syncthreads();
        {
            const size_t kb = ((size_t)bh*SS + kt0) * DD;
            for (int idx = t; idx < 2048; idx += 128)
                xkv[idx >> 6][idx & 63] = ksrc[kb + idx];   // raw u16 copy
        }
        __syncthreads();

        // k/v tile: thread covers rows jh*16..jh*16+15, column ecol
#pragma unroll
        for (int jj = 0; jj < 16; ++jj) {
            const int j = jh*16 + jj;
            float ak = 0.f, av = 0.f;
#pragma unroll
            for (int c = 0; c < 8; ++c) {
                uint4 xp = *reinterpret_cast<const uint4*>(&xkv[j][8*c]);
                uint4 kp = *reinterpret_cast<const uint4*>(&wk_lds[ecol][8*c]);
                uint4 vp = *reinterpret_cast<const uint4*>(&wv_lds[ecol][8*c]);
                float xf[8], kf[8], vf[8];
                unpack8(xp, xf); unpack8(kp, kf); unpack8(vp, vf);
#pragma unroll
                for (int d = 0; d < 8; ++d) {
                    ak += xf[d]*kf[d];
                    av += xf[d]*vf[d];
                }
            }
            k_lds[j][ecol] = ak + bk;
            v_lds[j][ecol] = av + bv;
        }
        __syncthreads();

        float s[32];
#pragma unroll
        for (int j = 0; j < 32; ++j) {
            float a = 0.f;
#pragma unroll
            for (int d = 0; d < 64; d += 4) {
                float4 k4 = *reinterpret_cast<const float4*>(&k_lds[j][d]);
                a += q[d]*k4.x + q[d+1]*k4.y + q[d+2]*k4.z + q[d+3]*k4.w;
            }
            s[j] = a;
        }
        float tm = m;
#pragma unroll
        for (int j = 0; j < 32; ++j) tm = fmaxf(tm, s[j]);
        const float alpha = __expf(m - tm);
        l *= alpha;
#pragma unroll
        for (int e = 0; e < 64; ++e) o[e] *= alpha;
#pragma unroll
        for (int j = 0; j < 32; ++j) {
            const float p = __expf(s[j] - tm);
            l += p;
#pragma unroll
            for (int d = 0; d < 64; d += 4) {
                float4 v4 = *reinterpret_cast<const float4*>(&v_lds[j][d]);
                o[d]   += p*v4.x;
                o[d+1] += p*v4.y;
                o[d+2] += p*v4.z;
                o[d+3] += p*v4.w;
            }
        }
        m = tm;
    }
    const float linv = 1.f / l;
#pragma unroll
    for (int e = 0; e < 64; ++e) o[e] *= linv;

    // ---- output projection: Wo (bf16) into wv_lds ----
    __syncthreads();
    for (int idx = t; idx < 4096; idx += 128)
        wv_lds[idx >> 6][idx & 63] = f2b(outw[(size_t)h*4096 + idx]);
    __syncthreads();

    u16 ob[8];
#pragma unroll
    for (int c = 0; c < 8; ++c) {
#pragma unroll
        for (int ee = 0; ee < 8; ++ee) {
            const int f = 8*c + ee;
            float a = 0.f;
#pragma unroll
            for (int cc = 0; cc < 8; ++cc) {
                uint4 wp = *reinterpret_cast<const uint4*>(&wv_lds[f][8*cc]);
                float wf[8]; unpack8(wp, wf);
#pragma unroll
                for (int e = 0; e < 8; ++e) a += o[8*cc + e] * wf[e];
            }
            ob[ee] = f2b(a + outb[h*64 + f]);
        }
        *reinterpret_cast<uint4*>(dst + qrow + 8*c) = *reinterpret_cast<const uint4*>(ob);
    }
}

// ---------------------------------------------------------------------------
// K3: final LN over concat(ci + ai, ct + at).  (R5-verified structure + adds)
// ---------------------------------------------------------------------------
__global__ __launch_bounds__(128)
void ln_concat_kernel(const u16* __restrict__ ci,
                      const u16* __restrict__ ct,
                      const u16* __restrict__ ai,
                      const u16* __restrict__ at,
                      const float* __restrict__ hng, const float* __restrict__ hnb,
                      float* __restrict__ outp)
{
    const int t = threadIdx.x;
    const int blk = blockIdx.x;           // B*H*4
    const int qt = blk & 3;
    const int bh = blk >> 2;
    const int h = bh & 15;
    const int q_idx = qt*128 + t;
    const size_t qrow = ((size_t)bh*SS + q_idx) * DD;

    float vals[128];
#pragma unroll
    for (int c = 0; c < 8; ++c) {
        uint4 a = *reinterpret_cast<const uint4*>(ci + qrow + 8*c);
        float fa[8]; unpack8(a, fa);
        uint4 d = *reinterpret_cast<const uint4*>(ai + qrow + 8*c);
        float fd[8]; unpack8(d, fd);
#pragma unroll
        for (int e = 0; e < 8; ++e) vals[8*c + e] = fa[e] + fd[e];

        uint4 b = *reinterpret_cast<const uint4*>(ct + qrow + 8*c);
        float fb[8]; unpack8(b, fb);
        uint4 g2 = *reinterpret_cast<const uint4*>(at + qrow + 8*c);
        float fg[8]; unpack8(g2, fg);
#pragma unroll
        for (int e = 0; e < 8; ++e) vals[64 + 8*c + e] = fb[e] + fg[e];
    }

    float s1 = 0.f, s2 = 0.f;
#pragma unroll
    for (int f = 0; f < 128; ++f) { s1 += vals[f]; s2 += vals[f]*vals[f]; }
    const float mu = s1 * (1.f/128.f);
    const float var = s2 * (1.f/128.f) - mu*mu;
    const float rstd = rsqrtf(var + 1e-5f);

    float* op = outp + ((size_t)bh*SS + q_idx) * 128;
#pragma unroll
    for (int c = 0; c < 32; ++c) {
        float ov[4];
#pragma unroll
        for (int e = 0; e < 4; ++e) {
            int f = 4*c + e;
            ov[e] = (vals[f] - mu)*rstd * hng[h*128 + f] + hnb[h*128 + f];
        }
        *reinterpret_cast<float4*>(op + 4*c) = make_float4(ov[0], ov[1], ov[2], ov[3]);
    }
}

// ---------------------------------------------------------------------------
extern "C" void kernel_launch(void* const* d_in, const int* in_sizes, int n_in,
                              void* d_out, int out_size, void* d_ws, size_t ws_size,
                              hipStream_t stream)
{
    const float* image_features = (const float*)d_in[0];
    const float* text_features  = (const float*)d_in[1];
    const float* img_w    = (const float*)d_in[2];
    const float* img_b    = (const float*)d_in[3];
    const float* img_ln_g = (const float*)d_in[4];
    const float* img_ln_b = (const float*)d_in[5];
    const float* txt_w    = (const float*)d_in[6];
    const float* txt_b    = (const float*)d_in[7];
    const float* txt_ln_g = (const float*)d_in[8];
    const float* txt_ln_b = (const float*)d_in[9];
    const float* i2t_in_w  = (const float*)d_in[10];
    const float* i2t_in_b  = (const float*)d_in[11];
    const float* i2t_out_w = (const float*)d_in[12];
    const float* i2t_out_b = (const float*)d_in[13];
    const float* t2i_in_w  = (const float*)d_in[14];
    const float* t2i_in_b  = (const float*)d_in[15];
    const float* t2i_out_w = (const float*)d_in[16];
    const float* t2i_out_b = (const float*)d_in[17];
    const float* hn_g = (const float*)d_in[18];
    const float* hn_b = (const float*)d_in[19];

    u16* ws = (u16*)d_ws;
    const size_t NBH = (size_t)BB*HH*SS*DD;   // 8,388,608 elems per buffer
    u16* ci = ws;                             // 16 MiB
    u16* ct = ws + NBH;                       // 16 MiB
    u16* ai = ws + 2*NBH;                     // 16 MiB
    u16* at = ws + 3*NBH;                     // 16 MiB (total 64 MiB)

    proj_ln_kernel<DI><<<dim3(2048), dim3(256), 0, stream>>>(
        image_features, img_w, img_b, img_ln_g, img_ln_b, ci);
    proj_ln_kernel<DT><<<dim3(2048), dim3(256), 0, stream>>>(
        text_features, txt_w, txt_b, txt_ln_g, txt_ln_b, ct);

    attn_kernel<<<dim3(2048), dim3(128), 0, stream>>>(
        ci, ct,
        i2t_in_w, i2t_in_b, i2t_out_w, i2t_out_b,
        t2i_in_w, t2i_in_b, t2i_out_w, t2i_out_b,
        ai, at);

    ln_concat_kernel<<<dim3(1024), dim3(128), 0, stream>>>(
        ci, ct, ai, at, hn_g, hn_b, (float*)d_out);
}

// Round 7
// 5054.288 us; speedup vs baseline: 2.1040x; 2.1040x over previous
//
#include <hip/hip_runtime.h>
#include <hip/hip_bf16.h>
#include <math.h>

#define BB 16
#define SS 512
#define HH 16
#define DD 64
#define HID 1024
#define DI 768
#define DT 512

typedef unsigned short u16;

__device__ __forceinline__ float b2f(u16 u) {
    return __uint_as_float(((unsigned int)u) << 16);
}
__device__ __forceinline__ u16 f2b(float f) {
    __hip_bfloat16 h = __float2bfloat16(f);
    return *reinterpret_cast<u16*>(&h);
}
__device__ __forceinline__ void unpack8(const uint4 p, float* f) {
    unsigned int u[4] = {p.x, p.y, p.z, p.w};
#pragma unroll
    for (int i = 0; i < 4; ++i) {
        f[2*i]   = __uint_as_float(u[i] << 16);
        f[2*i+1] = __uint_as_float(u[i] & 0xffff0000u);
    }
}

// ---------------------------------------------------------------------------
// K1: y = x @ W^T + b ; LayerNorm ; l2-normalize ; *0.125  (R5-verified math;
// this round: 2-stage register double-buffer on the weight loads)
// ---------------------------------------------------------------------------
template<int K>
__global__ __launch_bounds__(256)
void proj_ln_kernel(const float* __restrict__ x,
                    const float* __restrict__ w,
                    const float* __restrict__ bias,
                    const float* __restrict__ g,
                    const float* __restrict__ bln,
                    u16* __restrict__ outp)
{
    __shared__ float x_lds[4][K];
    __shared__ float y_lds[4][HID];
    const int t = threadIdx.x;
    const int row0 = blockIdx.x * 4;

    for (int idx = t; idx < K; idx += 256) {
        int r = idx / (K/4), c4 = idx % (K/4);
        reinterpret_cast<float4*>(&x_lds[r][0])[c4] =
            reinterpret_cast<const float4*>(x + (size_t)(row0 + r)*K)[c4];
    }
    __syncthreads();

    float acc[4][4];
#pragma unroll
    for (int a = 0; a < 4; ++a)
#pragma unroll
        for (int r = 0; r < 4; ++r) acc[a][r] = 0.f;

    const float* wr[4];
#pragma unroll
    for (int jj = 0; jj < 4; ++jj)
        wr[jj] = w + (size_t)(t + 256*jj)*K;

    float4 cw0[4], cw1[4];
#pragma unroll
    for (int jj = 0; jj < 4; ++jj) {
        cw0[jj] = *reinterpret_cast<const float4*>(wr[jj]);
        cw1[jj] = *reinterpret_cast<const float4*>(wr[jj] + 4);
    }

    for (int k0 = 0; k0 < K; k0 += 8) {
        const int kn = (k0 + 8 < K) ? (k0 + 8) : 0;   // dummy reload on last
        float4 nw0[4], nw1[4];
#pragma unroll
        for (int jj = 0; jj < 4; ++jj) {
            nw0[jj] = *reinterpret_cast<const float4*>(wr[jj] + kn);
            nw1[jj] = *reinterpret_cast<const float4*>(wr[jj] + kn + 4);
        }

        float xv[4][8];
#pragma unroll
        for (int r = 0; r < 4; ++r) {
            float4 a0 = *reinterpret_cast<const float4*>(&x_lds[r][k0]);
            float4 a1 = *reinterpret_cast<const float4*>(&x_lds[r][k0+4]);
            xv[r][0]=a0.x; xv[r][1]=a0.y; xv[r][2]=a0.z; xv[r][3]=a0.w;
            xv[r][4]=a1.x; xv[r][5]=a1.y; xv[r][6]=a1.z; xv[r][7]=a1.w;
        }
#pragma unroll
        for (int jj = 0; jj < 4; ++jj) {
            float wf[8] = {cw0[jj].x,cw0[jj].y,cw0[jj].z,cw0[jj].w,
                           cw1[jj].x,cw1[jj].y,cw1[jj].z,cw1[jj].w};
#pragma unroll
            for (int e = 0; e < 8; ++e)
#pragma unroll
                for (int r = 0; r < 4; ++r)
                    acc[jj][r] += xv[r][e] * wf[e];
        }
#pragma unroll
        for (int jj = 0; jj < 4; ++jj) { cw0[jj] = nw0[jj]; cw1[jj] = nw1[jj]; }
    }

#pragma unroll
    for (int jj = 0; jj < 4; ++jj) {
        float bj = bias[t + 256*jj];
#pragma unroll
        for (int r = 0; r < 4; ++r)
            y_lds[r][t + 256*jj] = acc[jj][r] + bj;
    }
    __syncthreads();

    const int lane = t & 63, wid = t >> 6;
    float s1 = 0.f, s2 = 0.f;
#pragma unroll
    for (int i = 0; i < 16; ++i) {
        float v = y_lds[wid][lane + 64*i];
        s1 += v; s2 += v*v;
    }
#pragma unroll
    for (int off = 32; off > 0; off >>= 1) {
        s1 += __shfl_down(s1, off);
        s2 += __shfl_down(s2, off);
    }
    s1 = __shfl(s1, 0); s2 = __shfl(s2, 0);
    const float mu = s1 * (1.f/1024.f);
    const float var = s2 * (1.f/1024.f) - mu*mu;
    const float rstd = rsqrtf(var + 1e-5f);

    float lv[16]; float sq = 0.f;
#pragma unroll
    for (int i = 0; i < 16; ++i) {
        int j = lane + 64*i;
        float z = (y_lds[wid][j] - mu) * rstd;
        lv[i] = z * g[j] + bln[j];
        sq += lv[i]*lv[i];
    }
#pragma unroll
    for (int off = 32; off > 0; off >>= 1) sq += __shfl_down(sq, off);
    sq = __shfl(sq, 0);
    const float sc = 0.125f / fmaxf(sqrtf(sq), 1e-12f);

    const int row = row0 + wid;
    const int b = row >> 9;
    const int s = row & 511;
#pragma unroll
    for (int i = 0; i < 16; ++i)
        outp[(((size_t)(b*HH + i)*SS + s) << 6) + lane] = f2b(lv[i] * sc);
}

// ---------------------------------------------------------------------------
// K2: K/V projection for one direction. Weights in registers (one out column
// per thread), input broadcast from LDS — conflict-free by construction.
// grid = B*H*8 (64-row tiles), 256 threads.
// ---------------------------------------------------------------------------
__global__ __launch_bounds__(256)
void kv_proj_kernel(const u16* __restrict__ inp,     // (B,H,S,D) bf16
                    const float* __restrict__ in_w,  // (H,192,64) fp32
                    const float* __restrict__ in_b,  // (H,192) fp32
                    u16* __restrict__ kout,
                    u16* __restrict__ vout)
{
    __shared__ float in_lds[64][64];
    const int t = threadIdx.x;
    const int blk = blockIdx.x;
    const int st = blk & 7;
    const int bh = blk >> 3;
    const int h = bh & 15;
    const size_t base = ((size_t)bh*SS + st*64) * DD;

    for (int idx = t; idx < 4096; idx += 256)
        in_lds[idx >> 6][idx & 63] = b2f(inp[base + idx]);

    const int e = t & 63;
    const int rb = t >> 6;

    float wk[64], wv[64];
    {
        const float* wkp = in_w + (size_t)h*12288 + (size_t)(64 + e)*64;
        const float* wvp = in_w + (size_t)h*12288 + (size_t)(128 + e)*64;
#pragma unroll
        for (int c = 0; c < 16; ++c) {
            float4 a = reinterpret_cast<const float4*>(wkp)[c];
            wk[4*c]=a.x; wk[4*c+1]=a.y; wk[4*c+2]=a.z; wk[4*c+3]=a.w;
            float4 b4 = reinterpret_cast<const float4*>(wvp)[c];
            wv[4*c]=b4.x; wv[4*c+1]=b4.y; wv[4*c+2]=b4.z; wv[4*c+3]=b4.w;
        }
    }
    const float bk = in_b[h*192 + 64 + e];
    const float bv = in_b[h*192 + 128 + e];
    __syncthreads();

#pragma unroll
    for (int jj = 0; jj < 16; ++jj) {
        const int r = rb*16 + jj;
        float ak = 0.f, av = 0.f;
#pragma unroll
        for (int d = 0; d < 64; d += 4) {
            float4 xq = *reinterpret_cast<const float4*>(&in_lds[r][d]);
            ak += xq.x*wk[d] + xq.y*wk[d+1] + xq.z*wk[d+2] + xq.w*wk[d+3];
            av += xq.x*wv[d] + xq.y*wv[d+1] + xq.z*wv[d+2] + xq.w*wv[d+3];
        }
        size_t o = base + (size_t)r*DD + e;
        kout[o] = f2b(ak + bk);
        vout[o] = f2b(av + bv);
    }
}

// ---------------------------------------------------------------------------
// K3: one cross-attention phase (flash, online softmax), K/V precomputed.
// All LDS reads are wave-uniform broadcasts — conflict-free. grid = B*H*4,
// 128 threads (thread = query row). Writes delta (pre-residual) bf16.
// ---------------------------------------------------------------------------
__global__ __launch_bounds__(128)
void attn_phase_kernel(const u16* __restrict__ qsrc,
                       const u16* __restrict__ kbuf,
                       const u16* __restrict__ vbuf,
                       const float* __restrict__ inw, const float* __restrict__ inb,
                       const float* __restrict__ outw, const float* __restrict__ outb,
                       u16* __restrict__ dst)
{
    __shared__ float w_lds[64][64];       // Wq then Wo (16 KB)
    __shared__ float k_lds[32][64];       // 8 KB
    __shared__ float v_lds[32][64];       // 8 KB

    const int t = threadIdx.x;
    const int blk = blockIdx.x;           // qt | bh
    const int qt = blk & 3;
    const int bh = blk >> 2;
    const int h = bh & 15;
    const int q_idx = qt*128 + t;
    const size_t qrow = ((size_t)bh*SS + q_idx) * DD;

    for (int idx = t; idx < 4096; idx += 128)
        w_lds[idx >> 6][idx & 63] = inw[(size_t)h*12288 + idx];
    __syncthreads();

    float xin[64];
#pragma unroll
    for (int c = 0; c < 8; ++c) {
        uint4 a = *reinterpret_cast<const uint4*>(qsrc + qrow + 8*c);
        unpack8(a, &xin[8*c]);
    }
    float q[64];
#pragma unroll
    for (int e = 0; e < 64; ++e) {
        float a = 0.f;
#pragma unroll
        for (int d = 0; d < 64; d += 4) {
            float4 w4 = *reinterpret_cast<const float4*>(&w_lds[e][d]);
            a += xin[d]*w4.x + xin[d+1]*w4.y + xin[d+2]*w4.z + xin[d+3]*w4.w;
        }
        q[e] = (a + inb[h*192 + e]) * 0.125f;
    }

    float m = -3.0e38f, l = 0.f;
    float o[64];
#pragma unroll
    for (int e = 0; e < 64; ++e) o[e] = 0.f;

    for (int kt0 = 0; kt0 < SS; kt0 += 32) {
        __syncthreads();
        {
            const size_t kb = ((size_t)bh*SS + kt0) * DD;
            for (int idx = t; idx < 2048; idx += 128) {
                k_lds[idx >> 6][idx & 63] = b2f(kbuf[kb + idx]);
                v_lds[idx >> 6][idx & 63] = b2f(vbuf[kb + idx]);
            }
        }
        __syncthreads();

        float s[32];
#pragma unroll
        for (int j = 0; j < 32; ++j) {
            float a = 0.f;
#pragma unroll
            for (int d = 0; d < 64; d += 4) {
                float4 k4 = *reinterpret_cast<const float4*>(&k_lds[j][d]);
                a += q[d]*k4.x + q[d+1]*k4.y + q[d+2]*k4.z + q[d+3]*k4.w;
            }
            s[j] = a;
        }
        float tm = m;
#pragma unroll
        for (int j = 0; j < 32; ++j) tm = fmaxf(tm, s[j]);
        const float alpha = __expf(m - tm);
        l *= alpha;
#pragma unroll
        for (int e = 0; e < 64; ++e) o[e] *= alpha;
#pragma unroll
        for (int j = 0; j < 32; ++j) {
            const float p = __expf(s[j] - tm);
            l += p;
#pragma unroll
            for (int d = 0; d < 64; d += 4) {
                float4 v4 = *reinterpret_cast<const float4*>(&v_lds[j][d]);
                o[d]   += p*v4.x;
                o[d+1] += p*v4.y;
                o[d+2] += p*v4.z;
                o[d+3] += p*v4.w;
            }
        }
        m = tm;
    }
    const float linv = 1.f / l;
#pragma unroll
    for (int e = 0; e < 64; ++e) o[e] *= linv;

    __syncthreads();
    for (int idx = t; idx < 4096; idx += 128)
        w_lds[idx >> 6][idx & 63] = outw[(size_t)h*4096 + idx];
    __syncthreads();

    u16 ob[8];
#pragma unroll
    for (int c = 0; c < 8; ++c) {
#pragma unroll
        for (int ee = 0; ee < 8; ++ee) {
            const int f = 8*c + ee;
            float a = 0.f;
#pragma unroll
            for (int e = 0; e < 64; e += 4) {
                float4 w4 = *reinterpret_cast<const float4*>(&w_lds[f][e]);
                a += o[e]*w4.x + o[e+1]*w4.y + o[e+2]*w4.z + o[e+3]*w4.w;
            }
            ob[ee] = f2b(a + outb[h*64 + f]);
        }
        *reinterpret_cast<uint4*>(dst + qrow + 8*c) = *reinterpret_cast<const uint4*>(ob);
    }
}

// ---------------------------------------------------------------------------
// K4: final LN over concat(ci + ai, ct + at).  (R5/R6-verified)
// ---------------------------------------------------------------------------
__global__ __launch_bounds__(128)
void ln_concat_kernel(const u16* __restrict__ ci,
                      const u16* __restrict__ ct,
                      const u16* __restrict__ ai,
                      const u16* __restrict__ at,
                      const float* __restrict__ hng, const float* __restrict__ hnb,
                      float* __restrict__ outp)
{
    const int t = threadIdx.x;
    const int blk = blockIdx.x;
    const int qt = blk & 3;
    const int bh = blk >> 2;
    const int h = bh & 15;
    const int q_idx = qt*128 + t;
    const size_t qrow = ((size_t)bh*SS + q_idx) * DD;

    float vals[128];
#pragma unroll
    for (int c = 0; c < 8; ++c) {
        uint4 a = *reinterpret_cast<const uint4*>(ci + qrow + 8*c);
        float fa[8]; unpack8(a, fa);
        uint4 d = *reinterpret_cast<const uint4*>(ai + qrow + 8*c);
        float fd[8]; unpack8(d, fd);
#pragma unroll
        for (int e = 0; e < 8; ++e) vals[8*c + e] = fa[e] + fd[e];

        uint4 b = *reinterpret_cast<const uint4*>(ct + qrow + 8*c);
        float fb[8]; unpack8(b, fb);
        uint4 g2 = *reinterpret_cast<const uint4*>(at + qrow + 8*c);
        float fg[8]; unpack8(g2, fg);
#pragma unroll
        for (int e = 0; e < 8; ++e) vals[64 + 8*c + e] = fb[e] + fg[e];
    }

    float s1 = 0.f, s2 = 0.f;
#pragma unroll
    for (int f = 0; f < 128; ++f) { s1 += vals[f]; s2 += vals[f]*vals[f]; }
    const float mu = s1 * (1.f/128.f);
    const float var = s2 * (1.f/128.f) - mu*mu;
    const float rstd = rsqrtf(var + 1e-5f);

    float* op = outp + ((size_t)bh*SS + q_idx) * 128;
#pragma unroll
    for (int c = 0; c < 32; ++c) {
        float ov[4];
#pragma unroll
        for (int e = 0; e < 4; ++e) {
            int f = 4*c + e;
            ov[e] = (vals[f] - mu)*rstd * hng[h*128 + f] + hnb[h*128 + f];
        }
        *reinterpret_cast<float4*>(op + 4*c) = make_float4(ov[0], ov[1], ov[2], ov[3]);
    }
}

// ---------------------------------------------------------------------------
extern "C" void kernel_launch(void* const* d_in, const int* in_sizes, int n_in,
                              void* d_out, int out_size, void* d_ws, size_t ws_size,
                              hipStream_t stream)
{
    const float* image_features = (const float*)d_in[0];
    const float* text_features  = (const float*)d_in[1];
    const float* img_w    = (const float*)d_in[2];
    const float* img_b    = (const float*)d_in[3];
    const float* img_ln_g = (const float*)d_in[4];
    const float* img_ln_b = (const float*)d_in[5];
    const float* txt_w    = (const float*)d_in[6];
    const float* txt_b    = (const float*)d_in[7];
    const float* txt_ln_g = (const float*)d_in[8];
    const float* txt_ln_b = (const float*)d_in[9];
    const float* i2t_in_w  = (const float*)d_in[10];
    const float* i2t_in_b  = (const float*)d_in[11];
    const float* i2t_out_w = (const float*)d_in[12];
    const float* i2t_out_b = (const float*)d_in[13];
    const float* t2i_in_w  = (const float*)d_in[14];
    const float* t2i_in_b  = (const float*)d_in[15];
    const float* t2i_out_w = (const float*)d_in[16];
    const float* t2i_out_b = (const float*)d_in[17];
    const float* hn_g = (const float*)d_in[18];
    const float* hn_b = (const float*)d_in[19];

    u16* ws = (u16*)d_ws;
    const size_t NBH = (size_t)BB*HH*SS*DD;   // 8,388,608 elems per buffer
    u16* ci = ws;                             // 16 MiB
    u16* ct = ws + NBH;
    u16* ai = ws + 2*NBH;
    u16* at = ws + 3*NBH;
    u16* kb = ws + 4*NBH;                     // shared K buffer (both phases)
    u16* vb = ws + 5*NBH;                     // shared V buffer (total 96 MiB)

    proj_ln_kernel<DI><<<dim3(2048), dim3(256), 0, stream>>>(
        image_features, img_w, img_b, img_ln_g, img_ln_b, ci);
    proj_ln_kernel<DT><<<dim3(2048), dim3(256), 0, stream>>>(
        text_features, txt_w, txt_b, txt_ln_g, txt_ln_b, ct);

    // ---- phase 0: i2t (queries=ci, keys/values from ct) ----
    kv_proj_kernel<<<dim3(2048), dim3(256), 0, stream>>>(
        ct, i2t_in_w, i2t_in_b, kb, vb);
    attn_phase_kernel<<<dim3(1024), dim3(128), 0, stream>>>(
        ci, kb, vb, i2t_in_w, i2t_in_b, i2t_out_w, i2t_out_b, ai);

    // ---- phase 1: t2i (queries=ct, keys/values from ci) ----
    kv_proj_kernel<<<dim3(2048), dim3(256), 0, stream>>>(
        ci, t2i_in_w, t2i_in_b, kb, vb);
    attn_phase_kernel<<<dim3(1024), dim3(128), 0, stream>>>(
        ct, kb, vb, t2i_in_w, t2i_in_b, t2i_out_w, t2i_out_b, at);

    ln_concat_kernel<<<dim3(1024), dim3(128), 0, stream>>>(
        ci, ct, ai, at, hn_g, hn_b, (float*)d_out);
}